// Round 12
// baseline (185.884 us; speedup 1.0000x reference)
//
#include <hip/hip_runtime.h>

// LQR KKT via temporally-parallel Riccati scan — FUSED single persistent
// kernel (64 blocks, device-scope atomic grid barrier) + register rollout.
//   Phase0: per-t element init (r11-proven body)
//   Phase1: 6 Hillis-Steele suffix-scan levels (r11-proven combine)
//   Phase2: K_t/M_t extraction (r11-proven body)
//   Phase3: block0 rollout x_{t+1}=M_t x_t — M rows in VGPRs, x broadcast via
//           v_readlane (zero LDS/DS on the chain)
//   Phase4: per-block u_t = -K_t x_t, mu_t = +/- P_t x_t
// Dims: n_state=32, n_input=16, n_all=48, T=64.  Anchor: r11 (138us).

namespace {

constexpr int NS  = 32;
constexpr int NI  = 16;
constexpr int NA  = 48;
constexpr int TT  = 64;
constexpr int NTH = 256;
constexpr int NBLK = 64;

__device__ __forceinline__ void fma4(float4& a, float s, const float4& b) {
  a.x += s * b.x; a.y += s * b.y; a.z += s * b.z; a.w += s * b.w;
}
__device__ __forceinline__ void fms4(float4& a, float s, const float4& b) {
  a.x -= s * b.x; a.y -= s * b.y; a.z -= s * b.z; a.w -= s * b.w;
}
__device__ __forceinline__ float dot4(const float4& a, const float4& b) {
  return a.x * b.x + a.y * b.y + a.z * b.z + a.w * b.w;
}
__device__ __forceinline__ float rdlane(float v, int l) {
  return __int_as_float(__builtin_amdgcn_readlane(__float_as_int(v), l));
}

template<int K>
__device__ __forceinline__ void tile_outer(const float* Acol0, int lda,
                                           const float* Bcol0, int ldb,
                                           float4 acc[4]) {
  #pragma unroll
  for (int m = 0; m < K; ++m) {
    const float4 va = *(const float4*)(Acol0 + m * lda);
    const float4 vb = *(const float4*)(Bcol0 + m * ldb);
    fma4(acc[0], va.x, vb); fma4(acc[1], va.y, vb);
    fma4(acc[2], va.z, vb); fma4(acc[3], va.w, vb);
  }
}

template<int KQ>
__device__ __forceinline__ void tile_dot(const float* Arow0, int lda,
                                         const float* Brow0, int ldb,
                                         float acc[4][4]) {
  #pragma unroll
  for (int q = 0; q < KQ; ++q) {
    float4 va[4], vb[4];
    #pragma unroll
    for (int r = 0; r < 4; ++r) va[r] = *(const float4*)(Arow0 + r * lda + 4 * q);
    #pragma unroll
    for (int c = 0; c < 4; ++c) vb[c] = *(const float4*)(Brow0 + c * ldb + 4 * q);
    #pragma unroll
    for (int r = 0; r < 4; ++r)
      #pragma unroll
      for (int c = 0; c < 4; ++c) acc[r][c] += dot4(va[r], vb[c]);
  }
}

// device-scope generation-counter grid barrier (Guideline 16 pattern).
__device__ __forceinline__ void gbar(unsigned* cnt, unsigned* gen) {
  __syncthreads();
  if (threadIdx.x == 0) {
    __threadfence();                          // release
    const unsigned g = atomicAdd(gen, 0u);
    const unsigned old = atomicAdd(cnt, 1u);
    if (old == NBLK - 1) {
      atomicExch(cnt, 0u);
      __threadfence();                        // order reset before bump
      atomicAdd(gen, 1u);
    } else {
      while (atomicAdd(gen, 0u) == g) __builtin_amdgcn_s_sleep(2);
    }
    __threadfence();                          // acquire
  }
  __syncthreads();
}

__device__ __forceinline__ float step_dot(const float4 m[8], float x) {
  float a0 = 0.f, a1 = 0.f, a2 = 0.f, a3 = 0.f;
  #pragma unroll
  for (int q = 0; q < 8; ++q) {
    a0 += rdlane(x, 4 * q + 0) * m[q].x;
    a1 += rdlane(x, 4 * q + 1) * m[q].y;
    a2 += rdlane(x, 4 * q + 2) * m[q].z;
    a3 += rdlane(x, 4 * q + 3) * m[q].w;
  }
  return (a0 + a1) + (a2 + a3);
}

__global__ __launch_bounds__(NTH, 1) void lqr_all(
    const float* __restrict__ A, const float* __restrict__ Bm,
    const float* __restrict__ C, const float* __restrict__ x0,
    float* __restrict__ out,
    float* __restrict__ Sb0, float* __restrict__ Sb1,
    float* __restrict__ Kall, float* __restrict__ Mall,
    float* __restrict__ xs, unsigned* __restrict__ bar) {
  // ---- LDS (union across phases; total ~95KB) ----
  __shared__ float sC [NA][NA];
  __shared__ float sAB[NS][NA];
  __shared__ float sRi[NI][NI];
  __shared__ float sRiST[NS][NI];
  __shared__ float sBRi [NS][NI];
  __shared__ float sAi[NS][NS], sCi[NS][NS], sJi[NS][NS];
  __shared__ float sAj[NS][NS], sCj[NS][NS], sJj[NS][NS], sAjT[NS][NS];
  __shared__ float sT1[NS][NS], sT1T[NS][NS];
  __shared__ float sY1[NS][NS], sY2[NS][NS], sY3T[NS][NS], sW[NS][NS];
  __shared__ float sX[NS][NS], sZm[NS][NS];
  __shared__ float sP[NS][NS], sG[NS][NA], sFu[NI][NA], sK[NI][NS];

  const int t = blockIdx.x, tid = threadIdx.x, lane = tid & 63, wid = tid >> 6;
  unsigned* cnt = bar;
  unsigned* gen = bar + 1;

  // ================= Phase 0: element init (r11-proven) =================
  {
    const float* Ct = C + (size_t)t * NA * NA;
    for (int e = tid; e < NA * NA; e += NTH) sC[e / NA][e % NA] = Ct[e];
    for (int e = tid; e < NS * NA; e += NTH) {
      int i = e / NA, j = e % NA;
      sAB[i][j] = (j < NS) ? A[i * NS + j] : Bm[i * NI + (j - NS)];
    }
    __syncthreads();
    if (wid == 0 && lane < 32) {      // GJ16: R^{-1}
      const int c = lane;
      float f[NI];
      #pragma unroll
      for (int i = 0; i < NI; ++i)
        f[i] = (c < NI) ? sC[NS + i][NS + c] : ((c - NI) == i ? 1.f : 0.f);
      #pragma unroll
      for (int k = 0; k < NI; ++k) {
        float mi[NI];
        #pragma unroll
        for (int i = 0; i < NI; ++i) mi[i] = rdlane(f[i], k);
        const float inv = 1.0f / mi[k];
        f[k] *= inv;
        #pragma unroll
        for (int i = 0; i < NI; ++i) if (i != k) f[i] -= mi[i] * f[k];
      }
      if (c >= NI) {
        #pragma unroll
        for (int i = 0; i < NI; ++i) sRi[i][c - NI] = f[i];
      }
    }
    __syncthreads();
    if (tid < 32) {                   // RiST = S R^{-1}
      const int a = tid >> 2, b = tid & 3;
      float acc[4][4];
      #pragma unroll
      for (int r = 0; r < 4; ++r)
        #pragma unroll
        for (int c = 0; c < 4; ++c) acc[r][c] = 0.f;
      tile_dot<4>(&sC[4 * a][NS], NA, &sRi[4 * b][0], NI, acc);
      #pragma unroll
      for (int r = 0; r < 4; ++r)
        *(float4*)&sRiST[4 * a + r][4 * b] =
            make_float4(acc[r][0], acc[r][1], acc[r][2], acc[r][3]);
    } else if (tid < 64) {            // BRi = B R^{-1}
      const int q = tid - 32, a = q >> 2, b = q & 3;
      float acc[4][4];
      #pragma unroll
      for (int r = 0; r < 4; ++r)
        #pragma unroll
        for (int c = 0; c < 4; ++c) acc[r][c] = 0.f;
      tile_dot<4>(&sAB[4 * a][NS], NA, &sRi[4 * b][0], NI, acc);
      #pragma unroll
      for (int r = 0; r < 4; ++r)
        *(float4*)&sBRi[4 * a + r][4 * b] =
            make_float4(acc[r][0], acc[r][1], acc[r][2], acc[r][3]);
    }
    __syncthreads();
    float* outA = Sb0 + (size_t)t * 3072;
    float* outC = outA + 1024;
    float* outJ = outA + 2048;
    if (tid < 64) {                   // J_e
      const int a = tid >> 3, b = tid & 7;
      float acc[4][4];
      #pragma unroll
      for (int r = 0; r < 4; ++r)
        #pragma unroll
        for (int c = 0; c < 4; ++c) acc[r][c] = 0.f;
      tile_dot<4>(&sRiST[4 * a][0], NI, &sC[4 * b][NS], NA, acc);
      #pragma unroll
      for (int r = 0; r < 4; ++r) {
        const float4 q4 = *(const float4*)&sC[4 * a + r][4 * b];
        *(float4*)(outJ + (4 * a + r) * NS + 4 * b) =
            make_float4(q4.x - acc[r][0], q4.y - acc[r][1],
                        q4.z - acc[r][2], q4.w - acc[r][3]);
      }
    } else if (tid < 128) {           // A_e
      const int q = tid - 64, a = q >> 3, b = q & 7;
      float acc[4][4];
      #pragma unroll
      for (int r = 0; r < 4; ++r)
        #pragma unroll
        for (int c = 0; c < 4; ++c) acc[r][c] = 0.f;
      tile_dot<4>(&sBRi[4 * a][0], NI, &sC[4 * b][NS], NA, acc);
      #pragma unroll
      for (int r = 0; r < 4; ++r) {
        const float4 a4 = *(const float4*)&sAB[4 * a + r][4 * b];
        *(float4*)(outA + (4 * a + r) * NS + 4 * b) =
            make_float4(a4.x - acc[r][0], a4.y - acc[r][1],
                        a4.z - acc[r][2], a4.w - acc[r][3]);
      }
    } else if (tid < 192) {           // C_e
      const int q = tid - 128, a = q >> 3, b = q & 7;
      float acc[4][4];
      #pragma unroll
      for (int r = 0; r < 4; ++r)
        #pragma unroll
        for (int c = 0; c < 4; ++c) acc[r][c] = 0.f;
      tile_dot<4>(&sBRi[4 * a][0], NI, &sAB[4 * b][NS], NA, acc);
      #pragma unroll
      for (int r = 0; r < 4; ++r)
        *(float4*)(outC + (4 * a + r) * NS + 4 * b) =
            make_float4(acc[r][0], acc[r][1], acc[r][2], acc[r][3]);
    }
  }
  gbar(cnt, gen);

  // ================= Phase 1: 6 suffix-scan levels (r11-proven) ============
  for (int l = 0; l < 6; ++l) {
    const int off = 1 << l;
    const float* Sin = (l & 1) ? Sb1 : Sb0;
    float* Sout = (l & 1) ? Sb0 : Sb1;
    const float* Ei = Sin + (size_t)t * 3072;
    float* Eo = Sout + (size_t)t * 3072;
    if (t + off >= TT) {              // copy-through
      const float4* src = (const float4*)Ei;
      float4* dst = (float4*)Eo;
      #pragma unroll
      for (int r = 0; r < 3; ++r) dst[tid + 256 * r] = src[tid + 256 * r];
    } else {
      const float* Ej = Sin + (size_t)(t + off) * 3072;
      { // Ph0: loads
        const float4* a4 = (const float4*)Ei;
        ((float4*)sAi)[tid] = a4[tid];
        ((float4*)sCi)[tid] = a4[256 + tid];
        ((float4*)sJi)[tid] = a4[512 + tid];
        const float4* b4 = (const float4*)Ej;
        ((float4*)sAj)[tid] = b4[tid];
        ((float4*)sCj)[tid] = b4[256 + tid];
        ((float4*)sJj)[tid] = b4[512 + tid];
      }
      __syncthreads();
      #pragma unroll
      for (int r = 0; r < 4; ++r) {
        const int e = tid + 256 * r, i = e >> 5, j = e & 31;
        sAjT[j][i] = sAj[i][j];
      }
      if (tid < 64) {                 // Ph1: X = I + Ci·Jj
        const int a = tid >> 3, b = tid & 7;
        float4 acc[4] = {make_float4(0,0,0,0), make_float4(0,0,0,0),
                         make_float4(0,0,0,0), make_float4(0,0,0,0)};
        tile_outer<NS>(&sCi[0][4 * a], NS, &sJj[0][4 * b], NS, acc);
        if (a == b) { acc[0].x += 1.f; acc[1].y += 1.f; acc[2].z += 1.f; acc[3].w += 1.f; }
        #pragma unroll
        for (int r = 0; r < 4; ++r) *(float4*)&sX[4 * a + r][4 * b] = acc[r];
      }
      __syncthreads();
      if (wid == 0) {                 // Ph2: GJ32 -> T1
        const int c = lane;
        float f[NS];
        #pragma unroll
        for (int i = 0; i < NS; ++i)
          f[i] = (c < NS) ? sX[i][c] : ((c - NS) == i ? 1.f : 0.f);
        #pragma unroll
        for (int k = 0; k < NS; ++k) {
          float mi[NS];
          #pragma unroll
          for (int i = 0; i < NS; ++i) mi[i] = rdlane(f[i], k);
          const float inv = 1.0f / mi[k];
          f[k] *= inv;
          #pragma unroll
          for (int i = 0; i < NS; ++i) if (i != k) f[i] -= mi[i] * f[k];
        }
        if (c >= NS) {
          const int col = c - NS;
          #pragma unroll
          for (int i = 0; i < NS; ++i) sT1[i][col] = f[i];
          #pragma unroll
          for (int q = 0; q < 8; ++q)
            *(float4*)&sT1T[col][4 * q] =
                make_float4(f[4 * q], f[4 * q + 1], f[4 * q + 2], f[4 * q + 3]);
        }
      }
      __syncthreads();
      if (tid < 192) {                // Ph3
        const int grp = tid >> 6, q = tid & 63, a = q >> 3, b = q & 7;
        float4 acc[4] = {make_float4(0,0,0,0), make_float4(0,0,0,0),
                         make_float4(0,0,0,0), make_float4(0,0,0,0)};
        if (grp == 0) {
          tile_outer<NS>(&sT1T[0][4 * a], NS, &sAi[0][4 * b], NS, acc);
          #pragma unroll
          for (int r = 0; r < 4; ++r) *(float4*)&sY1[4 * a + r][4 * b] = acc[r];
        } else if (grp == 1) {
          tile_outer<NS>(&sT1T[0][4 * a], NS, &sCi[0][4 * b], NS, acc);
          #pragma unroll
          for (int r = 0; r < 4; ++r) *(float4*)&sY2[4 * a + r][4 * b] = acc[r];
        } else {
          tile_outer<NS>(&sT1[0][4 * a], NS, &sJj[0][4 * b], NS, acc);
          #pragma unroll
          for (int r = 0; r < 4; ++r) *(float4*)&sY3T[4 * a + r][4 * b] = acc[r];
        }
      }
      __syncthreads();
      if (tid < 192) {                // Ph4
        const int grp = tid >> 6, q = tid & 63, a = q >> 3, b = q & 7;
        float4 acc[4] = {make_float4(0,0,0,0), make_float4(0,0,0,0),
                         make_float4(0,0,0,0), make_float4(0,0,0,0)};
        if (grp == 0) {
          tile_outer<NS>(&sAjT[0][4 * a], NS, &sY1[0][4 * b], NS, acc);
          #pragma unroll
          for (int r = 0; r < 4; ++r) *(float4*)&sX[4 * a + r][4 * b] = acc[r];
        } else if (grp == 1) {
          tile_outer<NS>(&sAjT[0][4 * a], NS, &sY2[0][4 * b], NS, acc);
          #pragma unroll
          for (int r = 0; r < 4; ++r) *(float4*)&sZm[4 * a + r][4 * b] = acc[r];
        } else {
          tile_outer<NS>(&sY3T[0][4 * a], NS, &sAi[0][4 * b], NS, acc);
          #pragma unroll
          for (int r = 0; r < 4; ++r) *(float4*)&sW[4 * a + r][4 * b] = acc[r];
        }
      }
      __syncthreads();
      if (tid < 64) {                 // Ph5: C'
        const int a = tid >> 3, b = tid & 7;
        float acc[4][4];
        #pragma unroll
        for (int r = 0; r < 4; ++r)
          #pragma unroll
          for (int c = 0; c < 4; ++c) acc[r][c] = 0.f;
        tile_dot<8>(&sZm[4 * a][0], NS, &sAj[4 * b][0], NS, acc);
        #pragma unroll
        for (int r = 0; r < 4; ++r) {
          const float4 c4 = *(const float4*)&sCj[4 * a + r][4 * b];
          *(float4*)&sY2[4 * a + r][4 * b] =
              make_float4(acc[r][0] + c4.x, acc[r][1] + c4.y,
                          acc[r][2] + c4.z, acc[r][3] + c4.w);
        }
      } else if (tid < 128) {         // Ph5: J'
        const int q = tid - 64, a = q >> 3, b = q & 7;
        float4 acc[4] = {make_float4(0,0,0,0), make_float4(0,0,0,0),
                         make_float4(0,0,0,0), make_float4(0,0,0,0)};
        tile_outer<NS>(&sAi[0][4 * a], NS, &sW[0][4 * b], NS, acc);
        #pragma unroll
        for (int r = 0; r < 4; ++r) {
          const float4 j4 = *(const float4*)&sJi[4 * a + r][4 * b];
          acc[r].x += j4.x; acc[r].y += j4.y; acc[r].z += j4.z; acc[r].w += j4.w;
          *(float4*)&sY1[4 * a + r][4 * b] = acc[r];
        }
      }
      __syncthreads();
      {                               // Ph6: store
        float4* o = (float4*)Eo;
        o[tid]       = ((const float4*)sX)[tid];
        o[256 + tid] = ((const float4*)sY2)[tid];
        o[512 + tid] = ((const float4*)sY1)[tid];
      }
    }
    gbar(cnt, gen);
  }

  // ================= Phase 2: kmat (r11-proven) ============================
  {
    for (int e = tid; e < NS * NA; e += NTH) {
      int i = e / NA, j = e % NA;
      sAB[i][j] = (j < NS) ? A[i * NS + j] : Bm[i * NI + (j - NS)];
    }
    if (t == TT - 1) {
      ((float4*)sP)[tid] = make_float4(0.f, 0.f, 0.f, 0.f);
    } else {
      const float4* j4 = (const float4*)(Sb0 + (size_t)(t + 1) * 3072 + 2048);
      ((float4*)sP)[tid] = j4[tid];
    }
    const int ui = tid / 12, uk = tid - 12 * ui;
    float4 cr0 = make_float4(0,0,0,0), cr1 = make_float4(0,0,0,0);
    float4 cr2 = make_float4(0,0,0,0), cr3 = make_float4(0,0,0,0);
    if (tid < 48) {
      const float* Ct = C + (size_t)t * NA * NA;
      cr0 = *(const float4*)&Ct[(NS + 4 * ui + 0) * NA + 4 * uk];
      cr1 = *(const float4*)&Ct[(NS + 4 * ui + 1) * NA + 4 * uk];
      cr2 = *(const float4*)&Ct[(NS + 4 * ui + 2) * NA + 4 * uk];
      cr3 = *(const float4*)&Ct[(NS + 4 * ui + 3) * NA + 4 * uk];
    }
    __syncthreads();
    if (tid < 96) {
      const int gi = tid / 12, gk = tid - 12 * gi;
      float4 acc[4] = {make_float4(0,0,0,0), make_float4(0,0,0,0),
                       make_float4(0,0,0,0), make_float4(0,0,0,0)};
      tile_outer<NS>(&sP[0][4 * gi], NS, &sAB[0][4 * gk], NA, acc);
      #pragma unroll
      for (int r = 0; r < 4; ++r) *(float4*)&sG[4 * gi + r][4 * gk] = acc[r];
    }
    __syncthreads();
    if (tid < 48) {
      float4 acc[4] = {cr0, cr1, cr2, cr3};
      tile_outer<NS>(&sAB[0][NS + 4 * ui], NA, &sG[0][4 * uk], NA, acc);
      #pragma unroll
      for (int r = 0; r < 4; ++r) *(float4*)&sFu[4 * ui + r][4 * uk] = acc[r];
    }
    __syncthreads();
    if (wid == 0) {                   // GJ16
      const int col = (lane < 16) ? (NS + lane) : (lane - 16);
      float f[NI];
      #pragma unroll
      for (int i = 0; i < NI; ++i) f[i] = sFu[i][col];
      #pragma unroll
      for (int k = 0; k < NI; ++k) {
        float mi[NI];
        #pragma unroll
        for (int i = 0; i < NI; ++i) mi[i] = rdlane(f[i], k);
        const float inv = 1.0f / mi[k];
        f[k] *= inv;
        #pragma unroll
        for (int i = 0; i < NI; ++i) if (i != k) f[i] -= mi[i] * f[k];
      }
      if (lane >= 16 && lane < 48) {
        const int b = lane - 16;
        #pragma unroll
        for (int i = 0; i < NI; ++i) {
          sK[i][b] = f[i];
          Kall[(size_t)t * NI * NS + i * NS + b] = f[i];
        }
      }
    }
    __syncthreads();
    if (tid < 64) {                   // M = A - B·K
      const int ma = tid >> 3, mb = tid & 7;
      float4 a0 = *(const float4*)&sAB[4 * ma + 0][4 * mb];
      float4 a1 = *(const float4*)&sAB[4 * ma + 1][4 * mb];
      float4 a2 = *(const float4*)&sAB[4 * ma + 2][4 * mb];
      float4 a3 = *(const float4*)&sAB[4 * ma + 3][4 * mb];
      #pragma unroll
      for (int q = 0; q < 4; ++q) {
        const float4 vf0 = *(const float4*)&sAB[4 * ma + 0][NS + 4 * q];
        const float4 vf1 = *(const float4*)&sAB[4 * ma + 1][NS + 4 * q];
        const float4 vf2 = *(const float4*)&sAB[4 * ma + 2][NS + 4 * q];
        const float4 vf3 = *(const float4*)&sAB[4 * ma + 3][NS + 4 * q];
        #pragma unroll
        for (int d = 0; d < 4; ++d) {
          const float4 vkk = *(const float4*)&sK[4 * q + d][4 * mb];
          const float s0 = (d == 0) ? vf0.x : (d == 1) ? vf0.y : (d == 2) ? vf0.z : vf0.w;
          const float s1 = (d == 0) ? vf1.x : (d == 1) ? vf1.y : (d == 2) ? vf1.z : vf1.w;
          const float s2 = (d == 0) ? vf2.x : (d == 1) ? vf2.y : (d == 2) ? vf2.z : vf2.w;
          const float s3 = (d == 0) ? vf3.x : (d == 1) ? vf3.y : (d == 2) ? vf3.z : vf3.w;
          fms4(a0, s0, vkk); fms4(a1, s1, vkk); fms4(a2, s2, vkk); fms4(a3, s3, vkk);
        }
      }
      float4* Mt = (float4*)(Mall + (size_t)t * NS * NS);
      Mt[(4 * ma + 0) * 8 + mb] = a0;
      Mt[(4 * ma + 1) * 8 + mb] = a1;
      Mt[(4 * ma + 2) * 8 + mb] = a2;
      Mt[(4 * ma + 3) * 8 + mb] = a3;
    }
  }
  gbar(cnt, gen);

  // ========== Phase 3: rollout (block 0, wave 0; M in VGPRs) ==============
  if (t == 0 && wid == 0) {
    const int i = lane;
    if (i < NS) {
      const float4* Mg = (const float4*)Mall;
      float4 mA[8], mB[8];
      float x = x0[i];
      out[i] = x; xs[i] = x;
      #pragma unroll
      for (int q = 0; q < 8; ++q) mA[q] = Mg[0 * 256 + i * 8 + q];
      #pragma unroll
      for (int q = 0; q < 8; ++q) mB[q] = Mg[1 * 256 + i * 8 + q];
      for (int s = 0; s < TT - 1; s += 2) {
        x = step_dot(mA, x);                       // step s (even)
        out[(s + 1) * NA + i] = x; xs[(s + 1) * NS + i] = x;
        if (s + 2 < TT - 1) {
          #pragma unroll
          for (int q = 0; q < 8; ++q) mA[q] = Mg[(s + 2) * 256 + i * 8 + q];
        }
        if (s + 1 < TT - 1) {
          x = step_dot(mB, x);                     // step s+1 (odd)
          out[(s + 2) * NA + i] = x; xs[(s + 2) * NS + i] = x;
          if (s + 3 < TT - 1) {
            #pragma unroll
            for (int q = 0; q < 8; ++q) mB[q] = Mg[(s + 3) * 256 + i * 8 + q];
          }
        }
      }
    }
  }
  gbar(cnt, gen);

  // ========== Phase 4: u_t / mu_t for t = blockIdx.x ======================
  {
    const float4* xr = (const float4*)(xs + (size_t)t * NS);
    if (tid < NI) {
      const float4* Kr = (const float4*)(Kall + (size_t)t * NI * NS + tid * NS);
      float acc = 0.f;
      #pragma unroll
      for (int q = 0; q < 8; ++q) acc += dot4(Kr[q], xr[q]);
      out[t * NA + NS + tid] = -acc;
    } else if (tid < NI + NS) {
      const int i = tid - NI;
      const float4* Pr = (const float4*)(Sb0 + (size_t)t * 3072 + 2048 + i * NS);
      float acc = 0.f;
      #pragma unroll
      for (int q = 0; q < 8; ++q) acc += dot4(Pr[q], xr[q]);
      out[NA * TT + t * NS + i] = (t == 0) ? -acc : acc;
    }
  }
}

} // namespace

extern "C" void kernel_launch(void* const* d_in, const int* in_sizes, int n_in,
                              void* d_out, int out_size, void* d_ws, size_t ws_size,
                              hipStream_t stream) {
  const float* A  = (const float*)d_in[0];
  const float* Bm = (const float*)d_in[1];
  const float* C  = (const float*)d_in[2];
  // d_in[3] is T (==64, compile-time constant here)
  const float* x0 = (const float*)d_in[4];
  float* out = (float*)d_out;

  float* Sb0  = (float*)d_ws;                          // 64*3072 floats
  float* Sb1  = Sb0 + (size_t)TT * 3072;               // 64*3072
  float* Kall = Sb1 + (size_t)TT * 3072;               // 64*512
  float* Mall = Kall + (size_t)TT * NI * NS;           // 64*1024
  float* xs   = Mall + (size_t)TT * NS * NS;           // 64*32
  unsigned* bar = (unsigned*)(xs + (size_t)TT * NS);   // 2 counters

  hipMemsetAsync(bar, 0, 8 * sizeof(unsigned), stream);
  hipLaunchKernelGGL(lqr_all, dim3(NBLK), dim3(NTH), 0, stream,
                     A, Bm, C, x0, out, Sb0, Sb1, Kall, Mall, xs, bar);
}

// Round 13
// 148.911 us; speedup vs baseline: 1.2483x; 1.2483x over previous
//
#include <hip/hip_runtime.h>

// LQR KKT via temporally-parallel Riccati scan — fused persistent kernel.
// Round-13 = r12 with the grid barrier rebuilt CONTENTION-FREE:
//   arrival: block b stores phase-id p to flags[b] (64 distinct words, no RMW)
//   collect: block0 lanes 0..63 poll flags with device-scope LOADS; store gen=p
//   wait:    other blocks poll gen with LOADS. Monotone p, no resets.
// Release/acquire __threadfence() pair kept byte-identical to r12 (proven to
// handle cross-XCD L2 staleness). All phase bodies byte-identical to r12.
// Dims: n_state=32, n_input=16, n_all=48, T=64.  Anchor: r11 (138us), r12 (186us).

namespace {

constexpr int NS  = 32;
constexpr int NI  = 16;
constexpr int NA  = 48;
constexpr int TT  = 64;
constexpr int NTH = 256;
constexpr int NBLK = 64;

__device__ __forceinline__ void fma4(float4& a, float s, const float4& b) {
  a.x += s * b.x; a.y += s * b.y; a.z += s * b.z; a.w += s * b.w;
}
__device__ __forceinline__ void fms4(float4& a, float s, const float4& b) {
  a.x -= s * b.x; a.y -= s * b.y; a.z -= s * b.z; a.w -= s * b.w;
}
__device__ __forceinline__ float dot4(const float4& a, const float4& b) {
  return a.x * b.x + a.y * b.y + a.z * b.z + a.w * b.w;
}
__device__ __forceinline__ float rdlane(float v, int l) {
  return __int_as_float(__builtin_amdgcn_readlane(__float_as_int(v), l));
}

template<int K>
__device__ __forceinline__ void tile_outer(const float* Acol0, int lda,
                                           const float* Bcol0, int ldb,
                                           float4 acc[4]) {
  #pragma unroll
  for (int m = 0; m < K; ++m) {
    const float4 va = *(const float4*)(Acol0 + m * lda);
    const float4 vb = *(const float4*)(Bcol0 + m * ldb);
    fma4(acc[0], va.x, vb); fma4(acc[1], va.y, vb);
    fma4(acc[2], va.z, vb); fma4(acc[3], va.w, vb);
  }
}

template<int KQ>
__device__ __forceinline__ void tile_dot(const float* Arow0, int lda,
                                         const float* Brow0, int ldb,
                                         float acc[4][4]) {
  #pragma unroll
  for (int q = 0; q < KQ; ++q) {
    float4 va[4], vb[4];
    #pragma unroll
    for (int r = 0; r < 4; ++r) va[r] = *(const float4*)(Arow0 + r * lda + 4 * q);
    #pragma unroll
    for (int c = 0; c < 4; ++c) vb[c] = *(const float4*)(Brow0 + c * ldb + 4 * q);
    #pragma unroll
    for (int r = 0; r < 4; ++r)
      #pragma unroll
      for (int c = 0; c < 4; ++c) acc[r][c] += dot4(va[r], vb[c]);
  }
}

// Contention-free device-scope grid barrier (store-flag / load-poll, monotone p).
__device__ __forceinline__ void gbar(unsigned* flags, unsigned* gen, unsigned p) {
  __syncthreads();
  if (threadIdx.x == 0) {
    __threadfence();                                    // release (L2 writeback)
    __hip_atomic_store(&flags[blockIdx.x], p, __ATOMIC_RELAXED,
                       __HIP_MEMORY_SCOPE_AGENT);
  }
  if (blockIdx.x == 0) {
    if (threadIdx.x < NBLK) {
      while (__hip_atomic_load(&flags[threadIdx.x], __ATOMIC_RELAXED,
                               __HIP_MEMORY_SCOPE_AGENT) < p)
        __builtin_amdgcn_s_sleep(1);
    }
    __syncthreads();
    if (threadIdx.x == 0)
      __hip_atomic_store(gen, p, __ATOMIC_RELAXED, __HIP_MEMORY_SCOPE_AGENT);
  } else if (threadIdx.x == 0) {
    while (__hip_atomic_load(gen, __ATOMIC_RELAXED,
                             __HIP_MEMORY_SCOPE_AGENT) < p)
      __builtin_amdgcn_s_sleep(1);
  }
  if (threadIdx.x == 0) __threadfence();                // acquire (L1/L2 inv)
  __syncthreads();
}

__device__ __forceinline__ float step_dot(const float4 m[8], float x) {
  float a0 = 0.f, a1 = 0.f, a2 = 0.f, a3 = 0.f;
  #pragma unroll
  for (int q = 0; q < 8; ++q) {
    a0 += rdlane(x, 4 * q + 0) * m[q].x;
    a1 += rdlane(x, 4 * q + 1) * m[q].y;
    a2 += rdlane(x, 4 * q + 2) * m[q].z;
    a3 += rdlane(x, 4 * q + 3) * m[q].w;
  }
  return (a0 + a1) + (a2 + a3);
}

__global__ __launch_bounds__(NTH, 1) void lqr_all(
    const float* __restrict__ A, const float* __restrict__ Bm,
    const float* __restrict__ C, const float* __restrict__ x0,
    float* __restrict__ out,
    float* __restrict__ Sb0, float* __restrict__ Sb1,
    float* __restrict__ Kall, float* __restrict__ Mall,
    float* __restrict__ xs, unsigned* __restrict__ bar) {
  __shared__ float sC [NA][NA];
  __shared__ float sAB[NS][NA];
  __shared__ float sRi[NI][NI];
  __shared__ float sRiST[NS][NI];
  __shared__ float sBRi [NS][NI];
  __shared__ float sAi[NS][NS], sCi[NS][NS], sJi[NS][NS];
  __shared__ float sAj[NS][NS], sCj[NS][NS], sJj[NS][NS], sAjT[NS][NS];
  __shared__ float sT1[NS][NS], sT1T[NS][NS];
  __shared__ float sY1[NS][NS], sY2[NS][NS], sY3T[NS][NS], sW[NS][NS];
  __shared__ float sX[NS][NS], sZm[NS][NS];
  __shared__ float sP[NS][NS], sG[NS][NA], sFu[NI][NA], sK[NI][NS];

  const int t = blockIdx.x, tid = threadIdx.x, lane = tid & 63, wid = tid >> 6;
  unsigned* flags = bar;          // [0..63]
  unsigned* gen   = bar + 64;     // separate cacheline
  unsigned p = 1;

  // ================= Phase 0: element init (r12-proven) =================
  {
    const float* Ct = C + (size_t)t * NA * NA;
    for (int e = tid; e < NA * NA; e += NTH) sC[e / NA][e % NA] = Ct[e];
    for (int e = tid; e < NS * NA; e += NTH) {
      int i = e / NA, j = e % NA;
      sAB[i][j] = (j < NS) ? A[i * NS + j] : Bm[i * NI + (j - NS)];
    }
    __syncthreads();
    if (wid == 0 && lane < 32) {      // GJ16: R^{-1}
      const int c = lane;
      float f[NI];
      #pragma unroll
      for (int i = 0; i < NI; ++i)
        f[i] = (c < NI) ? sC[NS + i][NS + c] : ((c - NI) == i ? 1.f : 0.f);
      #pragma unroll
      for (int k = 0; k < NI; ++k) {
        float mi[NI];
        #pragma unroll
        for (int i = 0; i < NI; ++i) mi[i] = rdlane(f[i], k);
        const float inv = 1.0f / mi[k];
        f[k] *= inv;
        #pragma unroll
        for (int i = 0; i < NI; ++i) if (i != k) f[i] -= mi[i] * f[k];
      }
      if (c >= NI) {
        #pragma unroll
        for (int i = 0; i < NI; ++i) sRi[i][c - NI] = f[i];
      }
    }
    __syncthreads();
    if (tid < 32) {                   // RiST = S R^{-1}
      const int a = tid >> 2, b = tid & 3;
      float acc[4][4];
      #pragma unroll
      for (int r = 0; r < 4; ++r)
        #pragma unroll
        for (int c = 0; c < 4; ++c) acc[r][c] = 0.f;
      tile_dot<4>(&sC[4 * a][NS], NA, &sRi[4 * b][0], NI, acc);
      #pragma unroll
      for (int r = 0; r < 4; ++r)
        *(float4*)&sRiST[4 * a + r][4 * b] =
            make_float4(acc[r][0], acc[r][1], acc[r][2], acc[r][3]);
    } else if (tid < 64) {            // BRi = B R^{-1}
      const int q = tid - 32, a = q >> 2, b = q & 3;
      float acc[4][4];
      #pragma unroll
      for (int r = 0; r < 4; ++r)
        #pragma unroll
        for (int c = 0; c < 4; ++c) acc[r][c] = 0.f;
      tile_dot<4>(&sAB[4 * a][NS], NA, &sRi[4 * b][0], NI, acc);
      #pragma unroll
      for (int r = 0; r < 4; ++r)
        *(float4*)&sBRi[4 * a + r][4 * b] =
            make_float4(acc[r][0], acc[r][1], acc[r][2], acc[r][3]);
    }
    __syncthreads();
    float* outA = Sb0 + (size_t)t * 3072;
    float* outC = outA + 1024;
    float* outJ = outA + 2048;
    if (tid < 64) {                   // J_e
      const int a = tid >> 3, b = tid & 7;
      float acc[4][4];
      #pragma unroll
      for (int r = 0; r < 4; ++r)
        #pragma unroll
        for (int c = 0; c < 4; ++c) acc[r][c] = 0.f;
      tile_dot<4>(&sRiST[4 * a][0], NI, &sC[4 * b][NS], NA, acc);
      #pragma unroll
      for (int r = 0; r < 4; ++r) {
        const float4 q4 = *(const float4*)&sC[4 * a + r][4 * b];
        *(float4*)(outJ + (4 * a + r) * NS + 4 * b) =
            make_float4(q4.x - acc[r][0], q4.y - acc[r][1],
                        q4.z - acc[r][2], q4.w - acc[r][3]);
      }
    } else if (tid < 128) {           // A_e
      const int q = tid - 64, a = q >> 3, b = q & 7;
      float acc[4][4];
      #pragma unroll
      for (int r = 0; r < 4; ++r)
        #pragma unroll
        for (int c = 0; c < 4; ++c) acc[r][c] = 0.f;
      tile_dot<4>(&sBRi[4 * a][0], NI, &sC[4 * b][NS], NA, acc);
      #pragma unroll
      for (int r = 0; r < 4; ++r) {
        const float4 a4 = *(const float4*)&sAB[4 * a + r][4 * b];
        *(float4*)(outA + (4 * a + r) * NS + 4 * b) =
            make_float4(a4.x - acc[r][0], a4.y - acc[r][1],
                        a4.z - acc[r][2], a4.w - acc[r][3]);
      }
    } else if (tid < 192) {           // C_e
      const int q = tid - 128, a = q >> 3, b = q & 7;
      float acc[4][4];
      #pragma unroll
      for (int r = 0; r < 4; ++r)
        #pragma unroll
        for (int c = 0; c < 4; ++c) acc[r][c] = 0.f;
      tile_dot<4>(&sBRi[4 * a][0], NI, &sAB[4 * b][NS], NA, acc);
      #pragma unroll
      for (int r = 0; r < 4; ++r)
        *(float4*)(outC + (4 * a + r) * NS + 4 * b) =
            make_float4(acc[r][0], acc[r][1], acc[r][2], acc[r][3]);
    }
  }
  gbar(flags, gen, p++);

  // ================= Phase 1: 6 suffix-scan levels (r12-proven) ============
  for (int l = 0; l < 6; ++l) {
    const int off = 1 << l;
    const float* Sin = (l & 1) ? Sb1 : Sb0;
    float* Sout = (l & 1) ? Sb0 : Sb1;
    const float* Ei = Sin + (size_t)t * 3072;
    float* Eo = Sout + (size_t)t * 3072;
    if (t + off >= TT) {              // copy-through
      const float4* src = (const float4*)Ei;
      float4* dst = (float4*)Eo;
      #pragma unroll
      for (int r = 0; r < 3; ++r) dst[tid + 256 * r] = src[tid + 256 * r];
    } else {
      const float* Ej = Sin + (size_t)(t + off) * 3072;
      {
        const float4* a4 = (const float4*)Ei;
        ((float4*)sAi)[tid] = a4[tid];
        ((float4*)sCi)[tid] = a4[256 + tid];
        ((float4*)sJi)[tid] = a4[512 + tid];
        const float4* b4 = (const float4*)Ej;
        ((float4*)sAj)[tid] = b4[tid];
        ((float4*)sCj)[tid] = b4[256 + tid];
        ((float4*)sJj)[tid] = b4[512 + tid];
      }
      __syncthreads();
      #pragma unroll
      for (int r = 0; r < 4; ++r) {
        const int e = tid + 256 * r, i = e >> 5, j = e & 31;
        sAjT[j][i] = sAj[i][j];
      }
      if (tid < 64) {                 // Ph1: X = I + Ci·Jj
        const int a = tid >> 3, b = tid & 7;
        float4 acc[4] = {make_float4(0,0,0,0), make_float4(0,0,0,0),
                         make_float4(0,0,0,0), make_float4(0,0,0,0)};
        tile_outer<NS>(&sCi[0][4 * a], NS, &sJj[0][4 * b], NS, acc);
        if (a == b) { acc[0].x += 1.f; acc[1].y += 1.f; acc[2].z += 1.f; acc[3].w += 1.f; }
        #pragma unroll
        for (int r = 0; r < 4; ++r) *(float4*)&sX[4 * a + r][4 * b] = acc[r];
      }
      __syncthreads();
      if (wid == 0) {                 // Ph2: GJ32 -> T1
        const int c = lane;
        float f[NS];
        #pragma unroll
        for (int i = 0; i < NS; ++i)
          f[i] = (c < NS) ? sX[i][c] : ((c - NS) == i ? 1.f : 0.f);
        #pragma unroll
        for (int k = 0; k < NS; ++k) {
          float mi[NS];
          #pragma unroll
          for (int i = 0; i < NS; ++i) mi[i] = rdlane(f[i], k);
          const float inv = 1.0f / mi[k];
          f[k] *= inv;
          #pragma unroll
          for (int i = 0; i < NS; ++i) if (i != k) f[i] -= mi[i] * f[k];
        }
        if (c >= NS) {
          const int col = c - NS;
          #pragma unroll
          for (int i = 0; i < NS; ++i) sT1[i][col] = f[i];
          #pragma unroll
          for (int q = 0; q < 8; ++q)
            *(float4*)&sT1T[col][4 * q] =
                make_float4(f[4 * q], f[4 * q + 1], f[4 * q + 2], f[4 * q + 3]);
        }
      }
      __syncthreads();
      if (tid < 192) {                // Ph3
        const int grp = tid >> 6, q = tid & 63, a = q >> 3, b = q & 7;
        float4 acc[4] = {make_float4(0,0,0,0), make_float4(0,0,0,0),
                         make_float4(0,0,0,0), make_float4(0,0,0,0)};
        if (grp == 0) {
          tile_outer<NS>(&sT1T[0][4 * a], NS, &sAi[0][4 * b], NS, acc);
          #pragma unroll
          for (int r = 0; r < 4; ++r) *(float4*)&sY1[4 * a + r][4 * b] = acc[r];
        } else if (grp == 1) {
          tile_outer<NS>(&sT1T[0][4 * a], NS, &sCi[0][4 * b], NS, acc);
          #pragma unroll
          for (int r = 0; r < 4; ++r) *(float4*)&sY2[4 * a + r][4 * b] = acc[r];
        } else {
          tile_outer<NS>(&sT1[0][4 * a], NS, &sJj[0][4 * b], NS, acc);
          #pragma unroll
          for (int r = 0; r < 4; ++r) *(float4*)&sY3T[4 * a + r][4 * b] = acc[r];
        }
      }
      __syncthreads();
      if (tid < 192) {                // Ph4
        const int grp = tid >> 6, q = tid & 63, a = q >> 3, b = q & 7;
        float4 acc[4] = {make_float4(0,0,0,0), make_float4(0,0,0,0),
                         make_float4(0,0,0,0), make_float4(0,0,0,0)};
        if (grp == 0) {
          tile_outer<NS>(&sAjT[0][4 * a], NS, &sY1[0][4 * b], NS, acc);
          #pragma unroll
          for (int r = 0; r < 4; ++r) *(float4*)&sX[4 * a + r][4 * b] = acc[r];
        } else if (grp == 1) {
          tile_outer<NS>(&sAjT[0][4 * a], NS, &sY2[0][4 * b], NS, acc);
          #pragma unroll
          for (int r = 0; r < 4; ++r) *(float4*)&sZm[4 * a + r][4 * b] = acc[r];
        } else {
          tile_outer<NS>(&sY3T[0][4 * a], NS, &sAi[0][4 * b], NS, acc);
          #pragma unroll
          for (int r = 0; r < 4; ++r) *(float4*)&sW[4 * a + r][4 * b] = acc[r];
        }
      }
      __syncthreads();
      if (tid < 64) {                 // Ph5: C'
        const int a = tid >> 3, b = tid & 7;
        float acc[4][4];
        #pragma unroll
        for (int r = 0; r < 4; ++r)
          #pragma unroll
          for (int c = 0; c < 4; ++c) acc[r][c] = 0.f;
        tile_dot<8>(&sZm[4 * a][0], NS, &sAj[4 * b][0], NS, acc);
        #pragma unroll
        for (int r = 0; r < 4; ++r) {
          const float4 c4 = *(const float4*)&sCj[4 * a + r][4 * b];
          *(float4*)&sY2[4 * a + r][4 * b] =
              make_float4(acc[r][0] + c4.x, acc[r][1] + c4.y,
                          acc[r][2] + c4.z, acc[r][3] + c4.w);
        }
      } else if (tid < 128) {         // Ph5: J'
        const int q = tid - 64, a = q >> 3, b = q & 7;
        float4 acc[4] = {make_float4(0,0,0,0), make_float4(0,0,0,0),
                         make_float4(0,0,0,0), make_float4(0,0,0,0)};
        tile_outer<NS>(&sAi[0][4 * a], NS, &sW[0][4 * b], NS, acc);
        #pragma unroll
        for (int r = 0; r < 4; ++r) {
          const float4 j4 = *(const float4*)&sJi[4 * a + r][4 * b];
          acc[r].x += j4.x; acc[r].y += j4.y; acc[r].z += j4.z; acc[r].w += j4.w;
          *(float4*)&sY1[4 * a + r][4 * b] = acc[r];
        }
      }
      __syncthreads();
      {
        float4* o = (float4*)Eo;
        o[tid]       = ((const float4*)sX)[tid];
        o[256 + tid] = ((const float4*)sY2)[tid];
        o[512 + tid] = ((const float4*)sY1)[tid];
      }
    }
    gbar(flags, gen, p++);
  }

  // ================= Phase 2: kmat (r12-proven) ============================
  {
    for (int e = tid; e < NS * NA; e += NTH) {
      int i = e / NA, j = e % NA;
      sAB[i][j] = (j < NS) ? A[i * NS + j] : Bm[i * NI + (j - NS)];
    }
    if (t == TT - 1) {
      ((float4*)sP)[tid] = make_float4(0.f, 0.f, 0.f, 0.f);
    } else {
      const float4* j4 = (const float4*)(Sb0 + (size_t)(t + 1) * 3072 + 2048);
      ((float4*)sP)[tid] = j4[tid];
    }
    const int ui = tid / 12, uk = tid - 12 * ui;
    float4 cr0 = make_float4(0,0,0,0), cr1 = make_float4(0,0,0,0);
    float4 cr2 = make_float4(0,0,0,0), cr3 = make_float4(0,0,0,0);
    if (tid < 48) {
      const float* Ct = C + (size_t)t * NA * NA;
      cr0 = *(const float4*)&Ct[(NS + 4 * ui + 0) * NA + 4 * uk];
      cr1 = *(const float4*)&Ct[(NS + 4 * ui + 1) * NA + 4 * uk];
      cr2 = *(const float4*)&Ct[(NS + 4 * ui + 2) * NA + 4 * uk];
      cr3 = *(const float4*)&Ct[(NS + 4 * ui + 3) * NA + 4 * uk];
    }
    __syncthreads();
    if (tid < 96) {
      const int gi = tid / 12, gk = tid - 12 * gi;
      float4 acc[4] = {make_float4(0,0,0,0), make_float4(0,0,0,0),
                       make_float4(0,0,0,0), make_float4(0,0,0,0)};
      tile_outer<NS>(&sP[0][4 * gi], NS, &sAB[0][4 * gk], NA, acc);
      #pragma unroll
      for (int r = 0; r < 4; ++r) *(float4*)&sG[4 * gi + r][4 * gk] = acc[r];
    }
    __syncthreads();
    if (tid < 48) {
      float4 acc[4] = {cr0, cr1, cr2, cr3};
      tile_outer<NS>(&sAB[0][NS + 4 * ui], NA, &sG[0][4 * uk], NA, acc);
      #pragma unroll
      for (int r = 0; r < 4; ++r) *(float4*)&sFu[4 * ui + r][4 * uk] = acc[r];
    }
    __syncthreads();
    if (wid == 0) {                   // GJ16
      const int col = (lane < 16) ? (NS + lane) : (lane - 16);
      float f[NI];
      #pragma unroll
      for (int i = 0; i < NI; ++i) f[i] = sFu[i][col];
      #pragma unroll
      for (int k = 0; k < NI; ++k) {
        float mi[NI];
        #pragma unroll
        for (int i = 0; i < NI; ++i) mi[i] = rdlane(f[i], k);
        const float inv = 1.0f / mi[k];
        f[k] *= inv;
        #pragma unroll
        for (int i = 0; i < NI; ++i) if (i != k) f[i] -= mi[i] * f[k];
      }
      if (lane >= 16 && lane < 48) {
        const int b = lane - 16;
        #pragma unroll
        for (int i = 0; i < NI; ++i) {
          sK[i][b] = f[i];
          Kall[(size_t)t * NI * NS + i * NS + b] = f[i];
        }
      }
    }
    __syncthreads();
    if (tid < 64) {                   // M = A - B·K
      const int ma = tid >> 3, mb = tid & 7;
      float4 a0 = *(const float4*)&sAB[4 * ma + 0][4 * mb];
      float4 a1 = *(const float4*)&sAB[4 * ma + 1][4 * mb];
      float4 a2 = *(const float4*)&sAB[4 * ma + 2][4 * mb];
      float4 a3 = *(const float4*)&sAB[4 * ma + 3][4 * mb];
      #pragma unroll
      for (int q = 0; q < 4; ++q) {
        const float4 vf0 = *(const float4*)&sAB[4 * ma + 0][NS + 4 * q];
        const float4 vf1 = *(const float4*)&sAB[4 * ma + 1][NS + 4 * q];
        const float4 vf2 = *(const float4*)&sAB[4 * ma + 2][NS + 4 * q];
        const float4 vf3 = *(const float4*)&sAB[4 * ma + 3][NS + 4 * q];
        #pragma unroll
        for (int d = 0; d < 4; ++d) {
          const float4 vkk = *(const float4*)&sK[4 * q + d][4 * mb];
          const float s0 = (d == 0) ? vf0.x : (d == 1) ? vf0.y : (d == 2) ? vf0.z : vf0.w;
          const float s1 = (d == 0) ? vf1.x : (d == 1) ? vf1.y : (d == 2) ? vf1.z : vf1.w;
          const float s2 = (d == 0) ? vf2.x : (d == 1) ? vf2.y : (d == 2) ? vf2.z : vf2.w;
          const float s3 = (d == 0) ? vf3.x : (d == 1) ? vf3.y : (d == 2) ? vf3.z : vf3.w;
          fms4(a0, s0, vkk); fms4(a1, s1, vkk); fms4(a2, s2, vkk); fms4(a3, s3, vkk);
        }
      }
      float4* Mt = (float4*)(Mall + (size_t)t * NS * NS);
      Mt[(4 * ma + 0) * 8 + mb] = a0;
      Mt[(4 * ma + 1) * 8 + mb] = a1;
      Mt[(4 * ma + 2) * 8 + mb] = a2;
      Mt[(4 * ma + 3) * 8 + mb] = a3;
    }
  }
  gbar(flags, gen, p++);

  // ========== Phase 3: rollout (block 0, wave 0; M in VGPRs) ==============
  if (t == 0 && wid == 0) {
    const int i = lane;
    if (i < NS) {
      const float4* Mg = (const float4*)Mall;
      float4 mA[8], mB[8];
      float x = x0[i];
      out[i] = x; xs[i] = x;
      #pragma unroll
      for (int q = 0; q < 8; ++q) mA[q] = Mg[0 * 256 + i * 8 + q];
      #pragma unroll
      for (int q = 0; q < 8; ++q) mB[q] = Mg[1 * 256 + i * 8 + q];
      for (int s = 0; s < TT - 1; s += 2) {
        x = step_dot(mA, x);
        out[(s + 1) * NA + i] = x; xs[(s + 1) * NS + i] = x;
        if (s + 2 < TT - 1) {
          #pragma unroll
          for (int q = 0; q < 8; ++q) mA[q] = Mg[(s + 2) * 256 + i * 8 + q];
        }
        if (s + 1 < TT - 1) {
          x = step_dot(mB, x);
          out[(s + 2) * NA + i] = x; xs[(s + 2) * NS + i] = x;
          if (s + 3 < TT - 1) {
            #pragma unroll
            for (int q = 0; q < 8; ++q) mB[q] = Mg[(s + 3) * 256 + i * 8 + q];
          }
        }
      }
    }
  }
  gbar(flags, gen, p++);

  // ========== Phase 4: u_t / mu_t for t = blockIdx.x ======================
  {
    const float4* xr = (const float4*)(xs + (size_t)t * NS);
    if (tid < NI) {
      const float4* Kr = (const float4*)(Kall + (size_t)t * NI * NS + tid * NS);
      float acc = 0.f;
      #pragma unroll
      for (int q = 0; q < 8; ++q) acc += dot4(Kr[q], xr[q]);
      out[t * NA + NS + tid] = -acc;
    } else if (tid < NI + NS) {
      const int i = tid - NI;
      const float4* Pr = (const float4*)(Sb0 + (size_t)t * 3072 + 2048 + i * NS);
      float acc = 0.f;
      #pragma unroll
      for (int q = 0; q < 8; ++q) acc += dot4(Pr[q], xr[q]);
      out[NA * TT + t * NS + i] = (t == 0) ? -acc : acc;
    }
  }
}

} // namespace

extern "C" void kernel_launch(void* const* d_in, const int* in_sizes, int n_in,
                              void* d_out, int out_size, void* d_ws, size_t ws_size,
                              hipStream_t stream) {
  const float* A  = (const float*)d_in[0];
  const float* Bm = (const float*)d_in[1];
  const float* C  = (const float*)d_in[2];
  // d_in[3] is T (==64, compile-time constant here)
  const float* x0 = (const float*)d_in[4];
  float* out = (float*)d_out;

  float* Sb0  = (float*)d_ws;                          // 64*3072 floats
  float* Sb1  = Sb0 + (size_t)TT * 3072;               // 64*3072
  float* Kall = Sb1 + (size_t)TT * 3072;               // 64*512
  float* Mall = Kall + (size_t)TT * NI * NS;           // 64*1024
  float* xs   = Mall + (size_t)TT * NS * NS;           // 64*32
  unsigned* bar = (unsigned*)(xs + (size_t)TT * NS);   // flags[64] + gen

  hipMemsetAsync(bar, 0, 128 * sizeof(unsigned), stream);
  hipLaunchKernelGGL(lqr_all, dim3(NBLK), dim3(NTH), 0, stream,
                     A, Bm, C, x0, out, Sb0, Sb1, Kall, Mall, xs, bar);
}